// Round 1
// baseline (1313.427 us; speedup 1.0000x reference)
//
#include <hip/hip_runtime.h>

// Ragged segment mean pooling: features [N, D=512] f32 -> out [B, D] f32.
// Memory-bound: 1.07 GB read, floor ~170 us at 6.3 TB/s achievable HBM BW.

#define SPLIT 256   // blocks per segment (row-split for parallelism)
#define TPB   128   // threads per block; TPB * 4 floats = D = 512 (one full row)

__global__ void zero_out_kernel(float* __restrict__ out, int n) {
    int i = blockIdx.x * blockDim.x + threadIdx.x;
    if (i < n) out[i] = 0.0f;
}

__global__ __launch_bounds__(TPB) void seg_mean_kernel(
        const int* __restrict__ lens,
        const float* __restrict__ feat,
        float* __restrict__ out,
        int B) {
    const int D = 512;
    const int seg   = blockIdx.x / SPLIT;
    const int split = blockIdx.x % SPLIT;

    // Segment start via tiny prefix loop (B=16; lens broadcast via scalar cache).
    long long start = 0;
    for (int b = 0; b < seg; ++b) start += lens[b];
    const int len = lens[seg];

    const int col = threadIdx.x * 4;   // each thread owns 4 consecutive columns
    const float* base = feat + start * (long long)D + col;

    float4 acc = make_float4(0.f, 0.f, 0.f, 0.f);
    // Blocks of this segment stride rows by SPLIT: at each iteration the SPLIT
    // blocks collectively stream a contiguous chunk of SPLIT rows (coalesced,
    // 16 B/lane float4 loads).
    for (int r = split; r < len; r += SPLIT) {
        float4 v = *(const float4*)(base + (long long)r * D);
        acc.x += v.x; acc.y += v.y; acc.z += v.z; acc.w += v.w;
    }

    // Fold the mean's divide into the partial before the atomic:
    // sum(acc_i) / len == sum(acc_i * (1/len)).
    const float inv = (len > 0) ? (1.0f / (float)len) : 0.0f;
    float* o = out + (long long)seg * D + col;
    atomicAdd(o + 0, acc.x * inv);
    atomicAdd(o + 1, acc.y * inv);
    atomicAdd(o + 2, acc.z * inv);
    atomicAdd(o + 3, acc.w * inv);
}

extern "C" void kernel_launch(void* const* d_in, const int* in_sizes, int n_in,
                              void* d_out, int out_size, void* d_ws, size_t ws_size,
                              hipStream_t stream) {
    const int*   lens = (const int*)d_in[0];     // stack_lengths [B] int32
    const float* feat = (const float*)d_in[1];   // features [N, D] float32
    float*       out  = (float*)d_out;           // [B, D] float32
    const int B = in_sizes[0];

    // d_out is poisoned to 0xAA before every call: zero it first (same stream
    // serializes kernel1 -> kernel2).
    zero_out_kernel<<<(out_size + 255) / 256, 256, 0, stream>>>(out, out_size);

    seg_mean_kernel<<<B * SPLIT, TPB, 0, stream>>>(lens, feat, out, B);
}